// Round 4
// baseline (139.110 us; speedup 1.0000x reference)
//
#include <hip/hip_runtime.h>

// ---------------- workspace layout (float offsets) ----------------
// V  : 2^14 x 16 vectors  (bits t=0..13, includes left fold)
// W  : 2^14 x 16 vectors  (bits t=50..63, includes right fold)
// P  : 4 chunks x 2^9 x 16x16 matrices, stored TRANSPOSED: P^T[idx][e*16+d]
// PACK: 131072 packed 64-bit sequence words
#define OFF_V    0u
#define OFF_W    262144u
#define OFF_P    524288u
#define OFF_VA   1048576u
#define OFF_WB   1050624u
#define OFF_PAV  1052672u
#define OFF_PAW  1085440u
#define OFF_PC0  1118208u
#define OFF_PC1  1150976u
#define OFF_PACK 1167360u
// total 1429504 floats = 5.45 MB of d_ws

__device__ __forceinline__ void rmul16(float* v, const float* B) {
  float nv[16];
#pragma unroll
  for (int e = 0; e < 16; ++e) {
    float a = 0.f;
#pragma unroll
    for (int d = 0; d < 16; ++d) a = fmaf(v[d], B[d * 16 + e], a);
    nv[e] = a;
  }
#pragma unroll
  for (int e = 0; e < 16; ++e) v[e] = nv[e];
}

__device__ __forceinline__ void lmul16(float* v, const float* B) {
  float nv[16];
#pragma unroll
  for (int d = 0; d < 16; ++d) {
    float a = 0.f;
#pragma unroll
    for (int e = 0; e < 16; ++e) a = fmaf(B[d * 16 + e], v[e], a);
    nv[d] = a;
  }
#pragma unroll
  for (int d = 0; d < 16; ++d) v[d] = nv[d];
}

// ---------------- phase A: piece chains only (29 blocks) ----------------
__global__ __launch_bounds__(256) void build_a(const float* __restrict__ left,
                                               const float* __restrict__ bulk,
                                               const float* __restrict__ right,
                                               float* __restrict__ ws) {
  int tid = threadIdx.x;
  __shared__ float Bs[2][256];
  __shared__ float Ls[2][16];
  __shared__ float Rs[2][16];
  for (int i = tid; i < 576; i += 256) {
    if (i < 512) Bs[i & 1][i >> 1] = bulk[i];
    else if (i < 544) { int j = i - 512; Ls[j & 1][j >> 1] = left[j]; }
    else              { int j = i - 544; Rs[j & 1][j >> 1] = right[j]; }
  }
  __syncthreads();

  unsigned gid = blockIdx.x * 256 + tid;
  float v[16];
  if (gid < 128) {
    unsigned i = gid;
#pragma unroll
    for (int d = 0; d < 16; ++d) v[d] = Ls[i & 1][d];
    for (int t = 1; t <= 6; ++t) rmul16(v, Bs[(i >> t) & 1]);
#pragma unroll
    for (int d = 0; d < 16; ++d) ws[OFF_VA + i * 16 + d] = v[d];
  } else if (gid < 256) {
    unsigned i = gid - 128;
#pragma unroll
    for (int d = 0; d < 16; ++d) v[d] = Rs[(i >> 6) & 1][d];
    for (int p = 5; p >= 0; --p) lmul16(v, Bs[(i >> p) & 1]);
#pragma unroll
    for (int d = 0; d < 16; ++d) ws[OFF_WB + i * 16 + d] = v[d];
  } else if (gid < 2304) {
    unsigned it = gid - 256, i = it >> 4, col = it & 15;
#pragma unroll
    for (int d = 0; d < 16; ++d) v[d] = Bs[(i >> 6) & 1][d * 16 + col];
    for (int p = 5; p >= 0; --p) lmul16(v, Bs[(i >> p) & 1]);
#pragma unroll
    for (int d = 0; d < 16; ++d) ws[OFF_PAV + i * 256 + d * 16 + col] = v[d];
  } else if (gid < 4352) {
    unsigned it = gid - 2304, i = it >> 4, col = it & 15;
#pragma unroll
    for (int d = 0; d < 16; ++d) v[d] = Bs[(i >> 6) & 1][d * 16 + col];
    for (int p = 5; p >= 0; --p) lmul16(v, Bs[(i >> p) & 1]);
#pragma unroll
    for (int d = 0; d < 16; ++d) ws[OFF_PAW + i * 256 + d * 16 + col] = v[d];
  } else {
    unsigned it = gid - 4352, c = it / 768, r = it - c * 768;
    if (r < 512) {
      unsigned i = r >> 4, col = r & 15;
#pragma unroll
      for (int d = 0; d < 16; ++d) v[d] = Bs[(i >> 4) & 1][d * 16 + col];
      for (int p = 3; p >= 0; --p) lmul16(v, Bs[(i >> p) & 1]);
#pragma unroll
      for (int d = 0; d < 16; ++d) ws[OFF_PC0 + c * 8192 + i * 256 + d * 16 + col] = v[d];
    } else {
      unsigned r2 = r - 512, i = r2 >> 4, col = r2 & 15;
#pragma unroll
      for (int d = 0; d < 16; ++d) v[d] = Bs[(i >> 3) & 1][d * 16 + col];
      for (int p = 2; p >= 0; --p) lmul16(v, Bs[(i >> p) & 1]);
#pragma unroll
      for (int d = 0; d < 16; ++d) ws[OFF_PC1 + c * 4096 + i * 256 + d * 16 + col] = v[d];
    }
  }
}

// ---------------- phase B: combines (blocks 0..4095) + x-pack (4096..4607) ----
__global__ __launch_bounds__(256) void build_b(const int* __restrict__ x,
                                               float* __restrict__ ws) {
  int tid = threadIdx.x;

  if (blockIdx.x >= 4096) {
    // ---- x-pack: ballot-transpose 33.5 MB of x into 1 MB of packed u64.
    // HBM stream overlaps the L2-bound combine work of blocks 0..4095.
    int lane = tid & 63;
    int wave = tid >> 6;
    unsigned pb = blockIdx.x - 4096;               // 0..511
    unsigned seqbase = pb * 256u + wave * 64u;     // 64 seqs per wave
    const int* __restrict__ xp = x + (size_t)seqbase * 64;
    unsigned long long word = 0ull;
#pragma unroll
    for (int rb = 0; rb < 8; ++rb) {
      int vals[8];
#pragma unroll
      for (int j = 0; j < 8; ++j) vals[j] = xp[(size_t)(rb * 8 + j) * 64 + lane];
#pragma unroll
      for (int j = 0; j < 8; ++j) {
        unsigned long long mm = __ballot(vals[j] & 1);
        if (lane == rb * 8 + j) word = mm;
      }
    }
    reinterpret_cast<unsigned long long*>(ws + OFF_PACK)[seqbase + lane] = word;
    return;
  }

  unsigned gid = blockIdx.x * 256 + tid;
  if (gid < 262144u) {
    // V[i][e] = sum_k VA[i&127][k] * PAV[i>>7][k][e]
    unsigned i = gid >> 4, e = gid & 15;
    const float* va = ws + OFF_VA + (i & 127) * 16;
    const float* pm = ws + OFF_PAV + (i >> 7) * 256;
    float a = 0.f;
#pragma unroll
    for (int k = 0; k < 16; ++k) a = fmaf(va[k], pm[k * 16 + e], a);
    ws[OFF_V + (size_t)i * 16 + e] = a;
  } else if (gid < 524288u) {
    // W[i][d] = sum_k PAW[i&127][d][k] * WB[i>>7][k]
    unsigned g = gid - 262144u, i = g >> 4, d = g & 15;
    const float* wb = ws + OFF_WB + (i >> 7) * 16;
    const float* pm = ws + OFF_PAW + (i & 127) * 256 + d * 16;
    float a = 0.f;
#pragma unroll
    for (int k = 0; k < 16; ++k) a = fmaf(pm[k], wb[k], a);
    ws[OFF_W + (size_t)i * 16 + d] = a;
  } else {
    // P^T_c[idx][e][d] = sum_k PC0[c][idx&31][d][k] * PC1[c][idx>>5][k][e]
    // thread = (c, idx, e, d) with d fastest: PC0 row-d read is per-lane
    // contiguous 64B (float4-vectorizable), PC1 column entry is a broadcast,
    // and the P^T write is 64B-coalesced.
    unsigned g = gid - 524288u;
    unsigned c = g >> 17, rem = g & 131071u;
    unsigned idx = rem >> 8, e = (rem >> 4) & 15, d = rem & 15;
    const float4* p0 =
        reinterpret_cast<const float4*>(ws + OFF_PC0 + c * 8192 + (idx & 31) * 256 + d * 16);
    const float* p1 = ws + OFF_PC1 + c * 4096 + (idx >> 5) * 256 + e;
    float4 r0 = p0[0], r1 = p0[1], r2 = p0[2], r3 = p0[3];
    float a;
    a = r0.x * p1[0];
    a = fmaf(r0.y, p1[16], a);
    a = fmaf(r0.z, p1[32], a);
    a = fmaf(r0.w, p1[48], a);
    a = fmaf(r1.x, p1[64], a);
    a = fmaf(r1.y, p1[80], a);
    a = fmaf(r1.z, p1[96], a);
    a = fmaf(r1.w, p1[112], a);
    a = fmaf(r2.x, p1[128], a);
    a = fmaf(r2.y, p1[144], a);
    a = fmaf(r2.z, p1[160], a);
    a = fmaf(r2.w, p1[176], a);
    a = fmaf(r3.x, p1[192], a);
    a = fmaf(r3.y, p1[208], a);
    a = fmaf(r3.z, p1[224], a);
    a = fmaf(r3.w, p1[240], a);
    ws[OFF_P + ((size_t)c << 17) + (size_t)idx * 256 + e * 16 + d] = a;
  }
}

// ---------------- main kernel: 16 lanes/seq, float4 gathers, shfl broadcast --
__global__ __launch_bounds__(256, 4) void mps_main(const float* __restrict__ ws,
                                                   float* __restrict__ out) {
  const int tid = threadIdx.x;
  const int lane = tid & 63;
  const int wave = tid >> 6;
  const int grp = lane >> 4;
  const int grpbase = lane & 48;
  const int e = lane & 15;
  const unsigned seqw = blockIdx.x * 16u + wave * 4u;

  // packed sequence word (nontemporal: read-once, keep tables in L2)
  unsigned long long bits = __builtin_nontemporal_load(
      reinterpret_cast<const unsigned long long*>(ws + OFF_PACK) + seqw + grp);

  const unsigned i0 = (unsigned)(bits & 0x3FFFull);
  const unsigned iw = (unsigned)(bits >> 50);

  // issue ALL gathers upfront — V, W scalars + 4 chunks x 4 float4 rows of P^T
  float mv = ws[OFF_V + (size_t)i0 * 16 + e];
  float w  = ws[OFF_W + (size_t)iw * 16 + e];

  float4 q[4][4];
#pragma unroll
  for (int ch = 0; ch < 4; ++ch) {
    unsigned idx = (unsigned)((bits >> (14 + 9 * ch)) & 511ull);
    const float4* pb = reinterpret_cast<const float4*>(ws + OFF_P + ((size_t)ch << 17)) +
                       (size_t)idx * 64 + e * 4;
    q[ch][0] = pb[0];
    q[ch][1] = pb[1];
    q[ch][2] = pb[2];
    q[ch][3] = pb[3];
  }

  // chunk matvecs: lane e holds P^T[e][0..15]; broadcast m via shfl (no LDS,
  // no memory-clobber barriers -> loads float freely above)
#pragma unroll
  for (int ch = 0; ch < 4; ++ch) {
    float a0, a1, a2, a3;
    {
      float4 qq = q[ch][0];
      a0 = __shfl(mv, grpbase + 0) * qq.x;
      a1 = __shfl(mv, grpbase + 1) * qq.y;
      a2 = __shfl(mv, grpbase + 2) * qq.z;
      a3 = __shfl(mv, grpbase + 3) * qq.w;
    }
#pragma unroll
    for (int j = 1; j < 4; ++j) {
      float4 qq = q[ch][j];
      a0 = fmaf(__shfl(mv, grpbase + j * 4 + 0), qq.x, a0);
      a1 = fmaf(__shfl(mv, grpbase + j * 4 + 1), qq.y, a1);
      a2 = fmaf(__shfl(mv, grpbase + j * 4 + 2), qq.z, a2);
      a3 = fmaf(__shfl(mv, grpbase + j * 4 + 3), qq.w, a3);
    }
    mv = (a0 + a1) + (a2 + a3);
  }

  // final dot with W vector, reduce across the 16-lane group
  float part = mv * w;
  part += __shfl_xor(part, 1, 64);
  part += __shfl_xor(part, 2, 64);
  part += __shfl_xor(part, 4, 64);
  part += __shfl_xor(part, 8, 64);
  if (e == 0) __builtin_nontemporal_store(part, out + seqw + grp);
}

extern "C" void kernel_launch(void* const* d_in, const int* in_sizes, int n_in,
                              void* d_out, int out_size, void* d_ws, size_t ws_size,
                              hipStream_t stream) {
  const int* x = (const int*)d_in[0];
  const float* left = (const float*)d_in[1];
  const float* bulk = (const float*)d_in[2];
  const float* right = (const float*)d_in[3];
  float* out = (float*)d_out;
  float* ws = (float*)d_ws;

  int nseq = in_sizes[0] / 64;  // 131072

  build_a<<<29, 256, 0, stream>>>(left, bulk, right, ws);
  build_b<<<4096 + nseq / 256, 256, 0, stream>>>(x, ws);
  mps_main<<<nseq / 16, 256, 0, stream>>>(ws, out);
}

// Round 5
// 137.101 us; speedup vs baseline: 1.0147x; 1.0147x over previous
//
#include <hip/hip_runtime.h>

// ---------------- workspace layout (float offsets) ----------------
// V  : 2^14 x 16 vectors  (bits t=0..13, includes left fold)
// W  : 2^14 x 16 vectors  (bits t=50..63, includes right fold)
// P  : 4 chunks x 2^9 x 16x16 matrices, stored TRANSPOSED: P^T[idx][e*16+d]
// PACK: 131072 packed 64-bit sequence words
#define OFF_V    0u
#define OFF_W    262144u
#define OFF_P    524288u
#define OFF_VA   1048576u
#define OFF_WB   1050624u
#define OFF_PAV  1052672u
#define OFF_PAW  1085440u
#define OFF_PC0  1118208u
#define OFF_PC1  1150976u
#define OFF_PACK 1167360u
// total 1429504 floats = 5.45 MB of d_ws

__device__ __forceinline__ void rmul16(float* v, const float* B) {
  float nv[16];
#pragma unroll
  for (int e = 0; e < 16; ++e) {
    float a = 0.f;
#pragma unroll
    for (int d = 0; d < 16; ++d) a = fmaf(v[d], B[d * 16 + e], a);
    nv[e] = a;
  }
#pragma unroll
  for (int e = 0; e < 16; ++e) v[e] = nv[e];
}

__device__ __forceinline__ void lmul16(float* v, const float* B) {
  float nv[16];
#pragma unroll
  for (int d = 0; d < 16; ++d) {
    float a = 0.f;
#pragma unroll
    for (int e = 0; e < 16; ++e) a = fmaf(B[d * 16 + e], v[e], a);
    nv[d] = a;
  }
#pragma unroll
  for (int d = 0; d < 16; ++d) v[d] = nv[d];
}

// ---------------- phase A: piece chains only (29 blocks) ----------------
__global__ __launch_bounds__(256) void build_a(const float* __restrict__ left,
                                               const float* __restrict__ bulk,
                                               const float* __restrict__ right,
                                               float* __restrict__ ws) {
  int tid = threadIdx.x;
  __shared__ float Bs[2][256];
  __shared__ float Ls[2][16];
  __shared__ float Rs[2][16];
  for (int i = tid; i < 576; i += 256) {
    if (i < 512) Bs[i & 1][i >> 1] = bulk[i];
    else if (i < 544) { int j = i - 512; Ls[j & 1][j >> 1] = left[j]; }
    else              { int j = i - 544; Rs[j & 1][j >> 1] = right[j]; }
  }
  __syncthreads();

  unsigned gid = blockIdx.x * 256 + tid;
  float v[16];
  if (gid < 128) {
    unsigned i = gid;
#pragma unroll
    for (int d = 0; d < 16; ++d) v[d] = Ls[i & 1][d];
    for (int t = 1; t <= 6; ++t) rmul16(v, Bs[(i >> t) & 1]);
#pragma unroll
    for (int d = 0; d < 16; ++d) ws[OFF_VA + i * 16 + d] = v[d];
  } else if (gid < 256) {
    unsigned i = gid - 128;
#pragma unroll
    for (int d = 0; d < 16; ++d) v[d] = Rs[(i >> 6) & 1][d];
    for (int p = 5; p >= 0; --p) lmul16(v, Bs[(i >> p) & 1]);
#pragma unroll
    for (int d = 0; d < 16; ++d) ws[OFF_WB + i * 16 + d] = v[d];
  } else if (gid < 2304) {
    unsigned it = gid - 256, i = it >> 4, col = it & 15;
#pragma unroll
    for (int d = 0; d < 16; ++d) v[d] = Bs[(i >> 6) & 1][d * 16 + col];
    for (int p = 5; p >= 0; --p) lmul16(v, Bs[(i >> p) & 1]);
#pragma unroll
    for (int d = 0; d < 16; ++d) ws[OFF_PAV + i * 256 + d * 16 + col] = v[d];
  } else if (gid < 4352) {
    unsigned it = gid - 2304, i = it >> 4, col = it & 15;
#pragma unroll
    for (int d = 0; d < 16; ++d) v[d] = Bs[(i >> 6) & 1][d * 16 + col];
    for (int p = 5; p >= 0; --p) lmul16(v, Bs[(i >> p) & 1]);
#pragma unroll
    for (int d = 0; d < 16; ++d) ws[OFF_PAW + i * 256 + d * 16 + col] = v[d];
  } else {
    unsigned it = gid - 4352, c = it / 768, r = it - c * 768;
    if (r < 512) {
      unsigned i = r >> 4, col = r & 15;
#pragma unroll
      for (int d = 0; d < 16; ++d) v[d] = Bs[(i >> 4) & 1][d * 16 + col];
      for (int p = 3; p >= 0; --p) lmul16(v, Bs[(i >> p) & 1]);
#pragma unroll
      for (int d = 0; d < 16; ++d) ws[OFF_PC0 + c * 8192 + i * 256 + d * 16 + col] = v[d];
    } else {
      unsigned r2 = r - 512, i = r2 >> 4, col = r2 & 15;
#pragma unroll
      for (int d = 0; d < 16; ++d) v[d] = Bs[(i >> 3) & 1][d * 16 + col];
      for (int p = 2; p >= 0; --p) lmul16(v, Bs[(i >> p) & 1]);
#pragma unroll
      for (int d = 0; d < 16; ++d) ws[OFF_PC1 + c * 4096 + i * 256 + d * 16 + col] = v[d];
    }
  }
}

// ---------------- phase B: combines (blocks 0..4095) + x-pack (4096..4607) ----
__global__ __launch_bounds__(256) void build_b(const int* __restrict__ x,
                                               float* __restrict__ ws) {
  int tid = threadIdx.x;

  if (blockIdx.x >= 4096) {
    // ---- x-pack: ballot-transpose 33.5 MB of x into 1 MB of packed u64.
    // HBM stream overlaps the L2-bound combine work of blocks 0..4095.
    int lane = tid & 63;
    int wave = tid >> 6;
    unsigned pb = blockIdx.x - 4096;               // 0..511
    unsigned seqbase = pb * 256u + wave * 64u;     // 64 seqs per wave
    const int* __restrict__ xp = x + (size_t)seqbase * 64;
    unsigned long long word = 0ull;
#pragma unroll
    for (int rb = 0; rb < 8; ++rb) {
      int vals[8];
#pragma unroll
      for (int j = 0; j < 8; ++j) vals[j] = xp[(size_t)(rb * 8 + j) * 64 + lane];
#pragma unroll
      for (int j = 0; j < 8; ++j) {
        unsigned long long mm = __ballot(vals[j] & 1);
        if (lane == rb * 8 + j) word = mm;
      }
    }
    reinterpret_cast<unsigned long long*>(ws + OFF_PACK)[seqbase + lane] = word;
    return;
  }

  unsigned gid = blockIdx.x * 256 + tid;
  if (gid < 262144u) {
    // V[i][e] = sum_k VA[i&127][k] * PAV[i>>7][k][e]
    unsigned i = gid >> 4, e = gid & 15;
    const float* va = ws + OFF_VA + (i & 127) * 16;
    const float* pm = ws + OFF_PAV + (i >> 7) * 256;
    float a = 0.f;
#pragma unroll
    for (int k = 0; k < 16; ++k) a = fmaf(va[k], pm[k * 16 + e], a);
    ws[OFF_V + (size_t)i * 16 + e] = a;
  } else if (gid < 524288u) {
    // W[i][d] = sum_k PAW[i&127][d][k] * WB[i>>7][k]
    unsigned g = gid - 262144u, i = g >> 4, d = g & 15;
    const float* wb = ws + OFF_WB + (i >> 7) * 16;
    const float* pm = ws + OFF_PAW + (i & 127) * 256 + d * 16;
    float a = 0.f;
#pragma unroll
    for (int k = 0; k < 16; ++k) a = fmaf(pm[k], wb[k], a);
    ws[OFF_W + (size_t)i * 16 + d] = a;
  } else {
    // P^T_c[idx][e][d] = sum_k PC0[c][idx&31][d][k] * PC1[c][idx>>5][k][e]
    unsigned g = gid - 524288u;
    unsigned c = g >> 17, rem = g & 131071u;
    unsigned idx = rem >> 8, e = (rem >> 4) & 15, d = rem & 15;
    const float4* p0 =
        reinterpret_cast<const float4*>(ws + OFF_PC0 + c * 8192 + (idx & 31) * 256 + d * 16);
    const float* p1 = ws + OFF_PC1 + c * 4096 + (idx >> 5) * 256 + e;
    float4 r0 = p0[0], r1 = p0[1], r2 = p0[2], r3 = p0[3];
    float a;
    a = r0.x * p1[0];
    a = fmaf(r0.y, p1[16], a);
    a = fmaf(r0.z, p1[32], a);
    a = fmaf(r0.w, p1[48], a);
    a = fmaf(r1.x, p1[64], a);
    a = fmaf(r1.y, p1[80], a);
    a = fmaf(r1.z, p1[96], a);
    a = fmaf(r1.w, p1[112], a);
    a = fmaf(r2.x, p1[128], a);
    a = fmaf(r2.y, p1[144], a);
    a = fmaf(r2.z, p1[160], a);
    a = fmaf(r2.w, p1[176], a);
    a = fmaf(r3.x, p1[192], a);
    a = fmaf(r3.y, p1[208], a);
    a = fmaf(r3.z, p1[224], a);
    a = fmaf(r3.w, p1[240], a);
    ws[OFF_P + ((size_t)c << 17) + (size_t)idx * 256 + e * 16 + d] = a;
  }
}

// ---- main: 16 lanes/seq, P^T float4 gathers upfront, LDS m-broadcast ----
__global__ __launch_bounds__(256, 4) void mps_main(const float* __restrict__ ws,
                                                   float* __restrict__ out) {
  __shared__ float sm[4][4][16];
  const int tid = threadIdx.x;
  const int lane = tid & 63;
  const int wave = tid >> 6;
  const int grp = lane >> 4;
  const int e = lane & 15;
  const unsigned seqw = blockIdx.x * 16u + wave * 4u;

  // broadcast load of this group's packed sequence word
  unsigned long long bits =
      reinterpret_cast<const unsigned long long*>(ws + OFF_PACK)[seqw + grp];

  const unsigned i0 = (unsigned)(bits & 0x3FFFull);
  const unsigned iw = (unsigned)(bits >> 50);

  // issue ALL gathers upfront — V, W scalars + 4 chunks x 4 float4 rows of P^T
  // (each instruction = one 1KB-coalesced read per 16-lane group)
  float mv = ws[OFF_V + (size_t)i0 * 16 + e];
  float w  = ws[OFF_W + (size_t)iw * 16 + e];

  float4 q[4][4];
#pragma unroll
  for (int ch = 0; ch < 4; ++ch) {
    unsigned idx = (unsigned)((bits >> (14 + 9 * ch)) & 511ull);
    const float4* pb = reinterpret_cast<const float4*>(ws + OFF_P + ((size_t)ch << 17)) +
                       (size_t)idx * 64 + e * 4;
    q[ch][0] = pb[0];
    q[ch][1] = pb[1];
    q[ch][2] = pb[2];
    q[ch][3] = pb[3];
  }

  // chunk matvecs: lane e holds P^T[e][0..15] (= column e of P); broadcast m
  // within each 16-lane group via wave-synchronous LDS round-trip
  // (5 DS ops/chunk vs 16 bpermutes — the R4 shfl version tripled DS traffic)
#pragma unroll
  for (int ch = 0; ch < 4; ++ch) {
    sm[wave][grp][e] = mv;
    asm volatile("" ::: "memory");
    float4 M0 = *(const float4*)&sm[wave][grp][0];
    float4 M1 = *(const float4*)&sm[wave][grp][4];
    float4 M2 = *(const float4*)&sm[wave][grp][8];
    float4 M3 = *(const float4*)&sm[wave][grp][12];
    asm volatile("" ::: "memory");
    float4 q0 = q[ch][0], q1 = q[ch][1], q2 = q[ch][2], q3 = q[ch][3];
    float a0 = M0.x * q0.x;
    float a1 = M0.y * q0.y;
    float a2 = M0.z * q0.z;
    float a3 = M0.w * q0.w;
    a0 = fmaf(M1.x, q1.x, a0);
    a1 = fmaf(M1.y, q1.y, a1);
    a2 = fmaf(M1.z, q1.z, a2);
    a3 = fmaf(M1.w, q1.w, a3);
    a0 = fmaf(M2.x, q2.x, a0);
    a1 = fmaf(M2.y, q2.y, a1);
    a2 = fmaf(M2.z, q2.z, a2);
    a3 = fmaf(M2.w, q2.w, a3);
    a0 = fmaf(M3.x, q3.x, a0);
    a1 = fmaf(M3.y, q3.y, a1);
    a2 = fmaf(M3.z, q3.z, a2);
    a3 = fmaf(M3.w, q3.w, a3);
    mv = (a0 + a1) + (a2 + a3);
  }

  // final dot with W vector, reduce across the 16-lane group
  float part = mv * w;
  part += __shfl_xor(part, 1, 64);
  part += __shfl_xor(part, 2, 64);
  part += __shfl_xor(part, 4, 64);
  part += __shfl_xor(part, 8, 64);
  if (e == 0) out[seqw + grp] = part;
}

extern "C" void kernel_launch(void* const* d_in, const int* in_sizes, int n_in,
                              void* d_out, int out_size, void* d_ws, size_t ws_size,
                              hipStream_t stream) {
  const int* x = (const int*)d_in[0];
  const float* left = (const float*)d_in[1];
  const float* bulk = (const float*)d_in[2];
  const float* right = (const float*)d_in[3];
  float* out = (float*)d_out;
  float* ws = (float*)d_ws;

  int nseq = in_sizes[0] / 64;  // 131072

  build_a<<<29, 256, 0, stream>>>(left, bulk, right, ws);
  build_b<<<4096 + nseq / 256, 256, 0, stream>>>(x, ws);
  mps_main<<<nseq / 16, 256, 0, stream>>>(ws, out);
}

// Round 6
// 120.340 us; speedup vs baseline: 1.1560x; 1.1393x over previous
//
#include <hip/hip_runtime.h>

// ---------------- workspace layout (float offsets) ----------------
// V  : 2^14 x 16 vectors  (bits t=0..13, includes left fold)
// W  : 2^14 x 16 vectors  (bits t=50..63, includes right fold)
// P  : 4 chunks x 2^9 x 16x16 matrices (bits t=14+9c .. 22+9c), row-major
#define OFF_V    0u
#define OFF_W    262144u
#define OFF_P    524288u
#define OFF_VA   1048576u
#define OFF_WB   1050624u
#define OFF_PAV  1052672u
#define OFF_PAW  1085440u
#define OFF_PC0  1118208u
#define OFF_PC1  1150976u
// total 1167360 floats = 4.46 MB of d_ws

__device__ __forceinline__ void rmul16(float* v, const float* B) {
  float nv[16];
#pragma unroll
  for (int e = 0; e < 16; ++e) {
    float a = 0.f;
#pragma unroll
    for (int d = 0; d < 16; ++d) a = fmaf(v[d], B[d * 16 + e], a);
    nv[e] = a;
  }
#pragma unroll
  for (int e = 0; e < 16; ++e) v[e] = nv[e];
}

__device__ __forceinline__ void lmul16(float* v, const float* B) {
  float nv[16];
#pragma unroll
  for (int d = 0; d < 16; ++d) {
    float a = 0.f;
#pragma unroll
    for (int e = 0; e < 16; ++e) a = fmaf(B[d * 16 + e], v[e], a);
    nv[d] = a;
  }
#pragma unroll
  for (int d = 0; d < 16; ++d) v[d] = nv[d];
}

// ---------------- phase A: small-depth piece chains ----------------
__global__ __launch_bounds__(256) void build_a(const float* __restrict__ left,
                                               const float* __restrict__ bulk,
                                               const float* __restrict__ right,
                                               float* __restrict__ ws) {
  __shared__ float Bs[2][256];
  __shared__ float Ls[2][16];
  __shared__ float Rs[2][16];
  int tid = threadIdx.x;
  for (int i = tid; i < 576; i += 256) {
    if (i < 512) Bs[i & 1][i >> 1] = bulk[i];
    else if (i < 544) { int j = i - 512; Ls[j & 1][j >> 1] = left[j]; }
    else              { int j = i - 544; Rs[j & 1][j >> 1] = right[j]; }
  }
  __syncthreads();

  unsigned gid = blockIdx.x * 256 + tid;
  float v[16];
  if (gid < 128) {
    unsigned i = gid;
#pragma unroll
    for (int d = 0; d < 16; ++d) v[d] = Ls[i & 1][d];
    for (int t = 1; t <= 6; ++t) rmul16(v, Bs[(i >> t) & 1]);
#pragma unroll
    for (int d = 0; d < 16; ++d) ws[OFF_VA + i * 16 + d] = v[d];
  } else if (gid < 256) {
    unsigned i = gid - 128;
#pragma unroll
    for (int d = 0; d < 16; ++d) v[d] = Rs[(i >> 6) & 1][d];
    for (int p = 5; p >= 0; --p) lmul16(v, Bs[(i >> p) & 1]);
#pragma unroll
    for (int d = 0; d < 16; ++d) ws[OFF_WB + i * 16 + d] = v[d];
  } else if (gid < 2304) {
    unsigned it = gid - 256, i = it >> 4, col = it & 15;
#pragma unroll
    for (int d = 0; d < 16; ++d) v[d] = Bs[(i >> 6) & 1][d * 16 + col];
    for (int p = 5; p >= 0; --p) lmul16(v, Bs[(i >> p) & 1]);
#pragma unroll
    for (int d = 0; d < 16; ++d) ws[OFF_PAV + i * 256 + d * 16 + col] = v[d];
  } else if (gid < 4352) {
    unsigned it = gid - 2304, i = it >> 4, col = it & 15;
#pragma unroll
    for (int d = 0; d < 16; ++d) v[d] = Bs[(i >> 6) & 1][d * 16 + col];
    for (int p = 5; p >= 0; --p) lmul16(v, Bs[(i >> p) & 1]);
#pragma unroll
    for (int d = 0; d < 16; ++d) ws[OFF_PAW + i * 256 + d * 16 + col] = v[d];
  } else {
    unsigned it = gid - 4352, c = it / 768, r = it - c * 768;
    if (r < 512) {
      unsigned i = r >> 4, col = r & 15;
#pragma unroll
      for (int d = 0; d < 16; ++d) v[d] = Bs[(i >> 4) & 1][d * 16 + col];
      for (int p = 3; p >= 0; --p) lmul16(v, Bs[(i >> p) & 1]);
#pragma unroll
      for (int d = 0; d < 16; ++d) ws[OFF_PC0 + c * 8192 + i * 256 + d * 16 + col] = v[d];
    } else {
      unsigned r2 = r - 512, i = r2 >> 4, col = r2 & 15;
#pragma unroll
      for (int d = 0; d < 16; ++d) v[d] = Bs[(i >> 3) & 1][d * 16 + col];
      for (int p = 2; p >= 0; --p) lmul16(v, Bs[(i >> p) & 1]);
#pragma unroll
      for (int d = 0; d < 16; ++d) ws[OFF_PC1 + c * 4096 + i * 256 + d * 16 + col] = v[d];
    }
  }
}

// ---------------- phase B: massively parallel combines ----------------
__global__ __launch_bounds__(256) void build_b(float* __restrict__ ws) {
  unsigned gid = blockIdx.x * 256 + threadIdx.x;
  if (gid < 262144u) {
    unsigned i = gid >> 4, e = gid & 15;
    const float* va = ws + OFF_VA + (i & 127) * 16;
    const float* pm = ws + OFF_PAV + (i >> 7) * 256;
    float a = 0.f;
#pragma unroll
    for (int k = 0; k < 16; ++k) a = fmaf(va[k], pm[k * 16 + e], a);
    ws[OFF_V + (size_t)i * 16 + e] = a;
  } else if (gid < 524288u) {
    unsigned g = gid - 262144u, i = g >> 4, d = g & 15;
    const float* wb = ws + OFF_WB + (i >> 7) * 16;
    const float* pm = ws + OFF_PAW + (i & 127) * 256 + d * 16;
    float a = 0.f;
#pragma unroll
    for (int k = 0; k < 16; ++k) a = fmaf(pm[k], wb[k], a);
    ws[OFF_W + (size_t)i * 16 + d] = a;
  } else {
    unsigned g = gid - 524288u;
    unsigned c = g >> 17, rem = g & 131071u;
    unsigned idx = rem >> 8, d = (rem >> 4) & 15, e = rem & 15;
    const float* p0 = ws + OFF_PC0 + c * 8192 + (idx & 31) * 256 + d * 16;
    const float* p1 = ws + OFF_PC1 + c * 4096 + (idx >> 5) * 256 + e;
    float a = 0.f;
#pragma unroll
    for (int k = 0; k < 16; ++k) a = fmaf(p0[k], p1[k * 16], a);
    ws[OFF_P + ((size_t)c << 17) + (size_t)idx * 256 + d * 16 + e] = a;
  }
}

// ---------------- main kernel: 16 lanes per sequence ----------------
// block 256 = 4 waves; each wave handles 4 sequences (lane e = output elem).
// All 4 chunk operand columns (64 scalars/lane) loaded upfront for MLP;
// per-chunk m-broadcast via wave-synchronous LDS roundtrip (no barrier).
__global__ __launch_bounds__(256, 4) void mps_main(const int* __restrict__ x,
                                                   const float* __restrict__ ws,
                                                   float* __restrict__ out) {
  __shared__ float sm[4][4][16];
  const int tid = threadIdx.x;
  const int lane = tid & 63;
  const int wave = tid >> 6;
  const int grp = lane >> 4;
  const int e = lane & 15;
  const unsigned seqw = blockIdx.x * 16u + wave * 4u;  // first seq of this wave
  const int* __restrict__ xp = x + (size_t)seqw * 64;

  // coalesced ballot-transpose: lane = column t, one row per ballot
  int v0 = xp[lane];
  int v1 = xp[64 + lane];
  int v2 = xp[128 + lane];
  int v3 = xp[192 + lane];
  unsigned long long b0 = __ballot(v0 & 1);
  unsigned long long b1 = __ballot(v1 & 1);
  unsigned long long b2 = __ballot(v2 & 1);
  unsigned long long b3 = __ballot(v3 & 1);
  unsigned long long bits = (grp & 2) ? ((grp & 1) ? b3 : b2)
                                      : ((grp & 1) ? b1 : b0);

  const unsigned i0 = (unsigned)(bits & 0x3FFFull);
  const unsigned iw = (unsigned)(bits >> 50);
  unsigned idx0 = (unsigned)((bits >> 14) & 511ull);
  unsigned idx1 = (unsigned)((bits >> 23) & 511ull);
  unsigned idx2 = (unsigned)((bits >> 32) & 511ull);
  unsigned idx3 = (unsigned)((bits >> 41) & 511ull);

  // issue ALL gathers upfront (V, W, 4x16 chunk columns) — max MLP,
  // each instruction is a 64B-coalesced line per 16-lane group
  float mv = ws[OFF_V + (size_t)i0 * 16 + e];
  float w  = ws[OFF_W + (size_t)iw * 16 + e];

  const float* __restrict__ P0 = ws + OFF_P;
  float p[4][16];
  {
    const float* pb = P0 + (size_t)idx0 * 256 + e;
#pragma unroll
    for (int d = 0; d < 16; ++d) p[0][d] = pb[d * 16];
  }
  {
    const float* pb = P0 + (1u << 17) + (size_t)idx1 * 256 + e;
#pragma unroll
    for (int d = 0; d < 16; ++d) p[1][d] = pb[d * 16];
  }
  {
    const float* pb = P0 + (2u << 17) + (size_t)idx2 * 256 + e;
#pragma unroll
    for (int d = 0; d < 16; ++d) p[2][d] = pb[d * 16];
  }
  {
    const float* pb = P0 + (3u << 17) + (size_t)idx3 * 256 + e;
#pragma unroll
    for (int d = 0; d < 16; ++d) p[3][d] = pb[d * 16];
  }

#pragma unroll
  for (int ch = 0; ch < 4; ++ch) {
    // wave-synchronous broadcast of m within each 16-lane group:
    // DS ops from one wave complete in order; asm barriers stop reordering.
    sm[wave][grp][e] = mv;
    asm volatile("" ::: "memory");
    float4 M0 = *(const float4*)&sm[wave][grp][0];
    float4 M1 = *(const float4*)&sm[wave][grp][4];
    float4 M2 = *(const float4*)&sm[wave][grp][8];
    float4 M3 = *(const float4*)&sm[wave][grp][12];
    asm volatile("" ::: "memory");
    float a0 = M0.x * p[ch][0];
    float a1 = M0.y * p[ch][1];
    float a2 = M0.z * p[ch][2];
    float a3 = M0.w * p[ch][3];
    a0 = fmaf(M1.x, p[ch][4], a0);
    a1 = fmaf(M1.y, p[ch][5], a1);
    a2 = fmaf(M1.z, p[ch][6], a2);
    a3 = fmaf(M1.w, p[ch][7], a3);
    a0 = fmaf(M2.x, p[ch][8], a0);
    a1 = fmaf(M2.y, p[ch][9], a1);
    a2 = fmaf(M2.z, p[ch][10], a2);
    a3 = fmaf(M2.w, p[ch][11], a3);
    a0 = fmaf(M3.x, p[ch][12], a0);
    a1 = fmaf(M3.y, p[ch][13], a1);
    a2 = fmaf(M3.z, p[ch][14], a2);
    a3 = fmaf(M3.w, p[ch][15], a3);
    mv = (a0 + a1) + (a2 + a3);
  }

  // final dot with W vector, reduce across the 16-lane group
  float part = mv * w;
  part += __shfl_xor(part, 1, 64);
  part += __shfl_xor(part, 2, 64);
  part += __shfl_xor(part, 4, 64);
  part += __shfl_xor(part, 8, 64);
  if (e == 0) out[seqw + grp] = part;
}

extern "C" void kernel_launch(void* const* d_in, const int* in_sizes, int n_in,
                              void* d_out, int out_size, void* d_ws, size_t ws_size,
                              hipStream_t stream) {
  const int* x = (const int*)d_in[0];
  const float* left = (const float*)d_in[1];
  const float* bulk = (const float*)d_in[2];
  const float* right = (const float*)d_in[3];
  float* out = (float*)d_out;
  float* ws = (float*)d_ws;

  int nseq = in_sizes[0] / 64;  // 131072

  build_a<<<29, 256, 0, stream>>>(left, bulk, right, ws);
  build_b<<<4096, 256, 0, stream>>>(ws);
  mps_main<<<nseq / 16, 256, 0, stream>>>(x, ws, out);
}